// Round 1
// baseline (428.677 us; speedup 1.0000x reference)
//
#include <hip/hip_runtime.h>

// ---------------- problem constants ----------------
constexpr int Bv = 2, Cv = 64, Hv = 192, Wv = 192;
constexpr int Hp = 194, Wp = 194;
constexpr int PLANE = Hp * Wp;            // 37636
constexpr int NCIN = 65;                  // 64 x-channels + depth
constexpr int Lv = Hv * Wv;               // 36864
constexpr int XP_SZ  = Bv * NCIN * PLANE; // padded input floats
constexpr int OFF_SZ = Bv * 18 * Lv;      // one offset partial

// ---------------- K0: build padded input ----------------
__global__ __launch_bounds__(256) void pad_kernel(
    const float* __restrict__ x, const float* __restrict__ depth,
    float* __restrict__ xp) {
  for (int idx = blockIdx.x * blockDim.x + threadIdx.x; idx < XP_SZ;
       idx += gridDim.x * blockDim.x) {
    int p  = idx % PLANE;
    int bc = idx / PLANE;
    int c  = bc % NCIN;
    int b  = bc / NCIN;
    int ph = p / Wp, pw = p % Wp;
    float v = 0.f;
    if (ph >= 1 && ph <= Hv && pw >= 1 && pw <= Wv) {
      int ih = ph - 1, iw = pw - 1;
      v = (c < Cv) ? x[((b * Cv + c) * Hv + ih) * Wv + iw]
                   : depth[(b * Hv + ih) * Wv + iw];
    }
    xp[idx] = v;
  }
}

// ---------------- K1: offset conv (2-way c-split partials) ----------------
// offp[g][b][t2][l] = sum over c in group g of conv taps (bias added later)
__global__ __launch_bounds__(256) void offconv_kernel(
    const float* __restrict__ xp, const float* __restrict__ wo,
    float* __restrict__ offp) {
  int g  = blockIdx.x / 288;          // c-group: 0 -> [0,33), 1 -> [33,65)
  int pb = blockIdx.x % 288;
  int c0  = g ? 33 : 0;
  int cnt = g ? 32 : 33;

  __shared__ float wT[33 * 9 * 20];   // [(c_l*9+k)][t2], padded stride 20
  int nw = cnt * 9 * 20;
  for (int e = threadIdx.x; e < nw; e += 256) {
    int t2 = e % 20;
    int ck = e / 20;
    float v = 0.f;
    if (t2 < 18) {
      int c_l = ck / 9, k = ck % 9;
      v = wo[t2 * 585 + (c0 + c_l) * 9 + k];
    }
    wT[e] = v;
  }
  __syncthreads();

  int P = pb * 256 + threadIdx.x;     // pixel id in [0, B*L)
  int b = P / Lv, l = P % Lv;
  int oh = l / Wv, ow = l % Wv;

  float acc[18];
#pragma unroll
  for (int t = 0; t < 18; ++t) acc[t] = 0.f;

  const float* xpb = xp + (b * NCIN + c0) * PLANE + oh * Wp + ow;
  for (int c_l = 0; c_l < cnt; ++c_l) {
    const float* xc = xpb + c_l * PLANE;
#pragma unroll
    for (int kh = 0; kh < 3; ++kh) {
#pragma unroll
      for (int kw = 0; kw < 3; ++kw) {
        float v = xc[kh * Wp + kw];
        const float* wrow = &wT[(c_l * 9 + kh * 3 + kw) * 20];
        float wv[20];
        *(float4*)&wv[0]  = *(const float4*)(wrow);
        *(float4*)&wv[4]  = *(const float4*)(wrow + 4);
        *(float4*)&wv[8]  = *(const float4*)(wrow + 8);
        *(float4*)&wv[12] = *(const float4*)(wrow + 12);
        *(float2*)&wv[16] = *(const float2*)(wrow + 16);
#pragma unroll
        for (int t = 0; t < 18; ++t) acc[t] += v * wv[t];
      }
    }
  }
  float* outp = offp + g * OFF_SZ + (b * 18) * Lv + l;
#pragma unroll
  for (int t = 0; t < 18; ++t) outp[t * Lv] = acc[t];
}

// ---------------- K2: fused bilinear gather + einsum ----------------
// Block = 64 consecutive pixels x all 64 output channels; fp32 4x4 reg tile.
__global__ __launch_bounds__(256) void main_kernel(
    const float* __restrict__ xp, const float* __restrict__ offp,
    const float* __restrict__ bias, const float* __restrict__ Wg,
    float* __restrict__ out) {
  int b    = blockIdx.x / 576;
  int tile = blockIdx.x % 576;
  int l0   = tile * 64;

  __shared__ int    s_idx[576];       // per (t, li): top-left gather index
  __shared__ float4 s_w4[576];        // per (t, li): 4 bilinear weights
  __shared__ float  s_vals[8 * 576];  // [c_l][t][li]
  __shared__ float  s_W[72 * 68];     // [i_local][o], padded stride 68

  int tid = threadIdx.x;

  // ---- phase 1: bilinear metadata (shared across all 64 channels) ----
  for (int e = tid; e < 576; e += 256) {
    int t = e / 64, li = e % 64;
    int l = l0 + li;
    int oh = l / Wv, ow = l % Wv;
    float ox = offp[(b * 18 + t) * Lv + l] +
               offp[OFF_SZ + (b * 18 + t) * Lv + l] + bias[t];
    float oy = offp[(b * 18 + 9 + t) * Lv + l] +
               offp[OFF_SZ + (b * 18 + 9 + t) * Lv + l] + bias[9 + t];
    float cx = (float)(oh + t / 3) + ox;   // base(oh+1) + delta(t/3-1) + off
    float cy = (float)(ow + t % 3) + oy;
    cx = fminf(fmaxf(cx, 0.f), 193.f);
    cy = fminf(fmaxf(cy, 0.f), 193.f);
    int tlx = (int)floorf(cx); tlx = min(max(tlx, 0), 192);
    int tly = (int)floorf(cy); tly = min(max(tly, 0), 192);
    float ax  = (float)(tlx + 1) - cx;
    float ay  = (float)(tly + 1) - cy;
    float bx_ = cx - (float)tlx;
    float by_ = cy - (float)tly;
    s_idx[e] = tlx * Wp + tly;
    s_w4[e]  = make_float4(ax * ay, ax * by_, bx_ * ay, bx_ * by_);
  }
  __syncthreads();

  float acc[4][4];
#pragma unroll
  for (int a = 0; a < 4; ++a)
#pragma unroll
    for (int j = 0; j < 4; ++j) acc[a][j] = 0.f;

  int lq = tid & 15;    // pixel quad  (inner for coalesced stores)
  int oq = tid >> 4;    // out-channel quad
  const float* xpb = xp + (b * NCIN) * PLANE;

  for (int ch = 0; ch < 8; ++ch) {
    // ---- gather 8 channels x 9 taps x 64 pixels into LDS ----
#pragma unroll
    for (int j = 0; j < 18; ++j) {
      int e2  = tid + j * 256;        // < 4608
      int c_l = e2 / 576, r = e2 % 576;
      const float* xc = xpb + (ch * 8 + c_l) * PLANE;
      int idx   = s_idx[r];
      float4 w4 = s_w4[r];
      float v = w4.x * xc[idx] + w4.y * xc[idx + 1] +
                w4.z * xc[idx + Wp] + w4.w * xc[idx + Wp + 1];
      s_vals[e2] = v;
    }
    // ---- stage W slice [72][64] ----
#pragma unroll
    for (int j = 0; j < 18; ++j) {
      int e2 = tid + j * 256;
      int i = e2 >> 6, o = e2 & 63;
      s_W[i * 68 + o] = Wg[o * 576 + ch * 72 + i];
    }
    __syncthreads();

    // ---- 4x4 register-tile matmul over the 72 i's of this chunk ----
#pragma unroll 9
    for (int i = 0; i < 72; ++i) {
      float4 v4 = *(const float4*)&s_vals[i * 64 + lq * 4];
      float4 w4 = *(const float4*)&s_W[i * 68 + oq * 4];
      float vv[4] = {v4.x, v4.y, v4.z, v4.w};
      float ww[4] = {w4.x, w4.y, w4.z, w4.w};
#pragma unroll
      for (int a = 0; a < 4; ++a)
#pragma unroll
        for (int j = 0; j < 4; ++j) acc[a][j] += ww[a] * vv[j];
    }
    __syncthreads();
  }

  // ---- store: float4 per output row ----
#pragma unroll
  for (int a = 0; a < 4; ++a) {
    int o = oq * 4 + a;
    float4 v = make_float4(acc[a][0], acc[a][1], acc[a][2], acc[a][3]);
    *(float4*)&out[(size_t)(b * Cv + o) * Lv + l0 + lq * 4] = v;
  }
}

// ---------------- launch ----------------
extern "C" void kernel_launch(void* const* d_in, const int* in_sizes, int n_in,
                              void* d_out, int out_size, void* d_ws, size_t ws_size,
                              hipStream_t stream) {
  const float* x     = (const float*)d_in[0];
  const float* depth = (const float*)d_in[1];
  const float* wo    = (const float*)d_in[2];
  const float* bias  = (const float*)d_in[3];
  const float* wgt   = (const float*)d_in[4];
  float* out  = (float*)d_out;
  float* xp   = (float*)d_ws;
  float* offp = xp + XP_SZ;

  pad_kernel<<<2048, 256, 0, stream>>>(x, depth, xp);
  offconv_kernel<<<576, 256, 0, stream>>>(xp, wo, offp);
  main_kernel<<<1152, 256, 0, stream>>>(xp, offp, bias, wgt, out);
}

// Round 4
// 216.626 us; speedup vs baseline: 1.9789x; 1.9789x over previous
//
#include <hip/hip_runtime.h>

// ---------------- problem constants ----------------
constexpr int Bv = 2, Cv = 64, Hv = 192, Wv = 192;
constexpr int Hp = 194, Wp = 194;
constexpr int PLANE = Hp * Wp;            // 37636
constexpr int NCIN = 65;                  // 64 x-channels + depth
constexpr int Lv = Hv * Wv;               // 36864
constexpr int XP_SZ  = Bv * NCIN * PLANE; // padded input floats
constexpr int OFF_SZ = Bv * 18 * Lv;      // one offset partial (floats)
constexpr int NMETA  = Bv * 9 * Lv;       // 663552

typedef __attribute__((ext_vector_type(8))) short short8;
typedef __attribute__((ext_vector_type(4))) float f32x4;

__device__ __forceinline__ unsigned short f2b(float v) {
  unsigned u = __float_as_uint(v);
  u = (u + 0x7FFFu + ((u >> 16) & 1u)) >> 16;   // RNE
  return (unsigned short)u;
}

// ---------------- K0: build padded input ----------------
__global__ __launch_bounds__(256) void pad_kernel(
    const float* __restrict__ x, const float* __restrict__ depth,
    float* __restrict__ xp) {
  for (int idx = blockIdx.x * blockDim.x + threadIdx.x; idx < XP_SZ;
       idx += gridDim.x * blockDim.x) {
    int p  = idx % PLANE;
    int bc = idx / PLANE;
    int c  = bc % NCIN;
    int b  = bc / NCIN;
    int ph = p / Wp, pw = p % Wp;
    float v = 0.f;
    if (ph >= 1 && ph <= Hv && pw >= 1 && pw <= Wv) {
      int ih = ph - 1, iw = pw - 1;
      v = (c < Cv) ? x[((b * Cv + c) * Hv + ih) * Wv + iw]
                   : depth[(b * Hv + ih) * Wv + iw];
    }
    xp[idx] = v;
  }
}

// ---------------- K0b: prep (W -> bf16, wo -> transposed) ----------------
__global__ __launch_bounds__(256) void prep_kernel(
    const float* __restrict__ Wg, const float* __restrict__ wo,
    unsigned short* __restrict__ Wb, float* __restrict__ woT) {
  int n = blockIdx.x * 256 + threadIdx.x;
  if (n < 64 * 576) Wb[n] = f2b(Wg[n]);
  if (n < 585 * 18) {                 // woT[ck][t] = wo[t][ck]
    int ck = n / 18, t = n - ck * 18;
    woT[n] = wo[t * 585 + ck];
  }
}

// ---------------- K1: offset conv (2-way c-split partials) ----------------
// Weights read via wave-uniform addresses (scalarizable); acc[18] only.
__global__ __launch_bounds__(256) void offconv_kernel(
    const float* __restrict__ xp, const float* __restrict__ woT,
    float* __restrict__ offp) {
  int g  = blockIdx.x / 288;          // c-group: 0 -> [0,33), 1 -> [33,65)
  int pb = blockIdx.x % 288;
  int c0  = g ? 33 : 0;
  int cnt = g ? 32 : 33;

  int P = pb * 256 + threadIdx.x;     // pixel id in [0, B*L)
  int b = P / Lv, l = P % Lv;
  int oh = l / Wv, ow = l % Wv;

  float acc[18];
#pragma unroll
  for (int t = 0; t < 18; ++t) acc[t] = 0.f;

  const float* xpb = xp + (b * NCIN + c0) * PLANE + oh * Wp + ow;
  const float* wp  = woT + c0 * 9 * 18;
  for (int cl = 0; cl < cnt; ++cl) {
    const float* xc = xpb + cl * PLANE;
#pragma unroll
    for (int kh = 0; kh < 3; ++kh)
#pragma unroll
      for (int kw = 0; kw < 3; ++kw) {
        float v = xc[kh * Wp + kw];
        const float* wr = wp + (cl * 9 + kh * 3 + kw) * 18;  // uniform addr
#pragma unroll
        for (int t = 0; t < 18; ++t) acc[t] += v * wr[t];
      }
  }
  float* op = offp + g * OFF_SZ + b * 18 * Lv + l;
#pragma unroll
  for (int t = 0; t < 18; ++t) op[t * Lv] = acc[t];
}

// ---------------- K1b: combine partials -> bilinear metadata ----------------
__global__ __launch_bounds__(256) void meta_kernel(
    const float* __restrict__ offp, const float* __restrict__ bias,
    int* __restrict__ midx, float2* __restrict__ mfxy) {
  int n = blockIdx.x * 256 + threadIdx.x;     // < NMETA exactly
  int b = n / (9 * Lv);
  int r = n - b * 9 * Lv;
  int t = r / Lv;
  int l = r - t * Lv;
  int oh = l / Wv, ow = l % Wv;

  float ox = offp[(b * 18 + t) * Lv + l] +
             offp[OFF_SZ + (b * 18 + t) * Lv + l] + bias[t];
  float oy = offp[(b * 18 + 9 + t) * Lv + l] +
             offp[OFF_SZ + (b * 18 + 9 + t) * Lv + l] + bias[9 + t];
  float cx = (float)(oh + t / 3) + ox;     // base(oh+1)+delta(t/3-1)+off
  float cy = (float)(ow + t % 3) + oy;
  cx = fminf(fmaxf(cx, 0.f), 193.f);
  cy = fminf(fmaxf(cy, 0.f), 193.f);
  int tlx = min((int)cx, 192);             // cx>=0 -> trunc == floor
  int tly = min((int)cy, 192);
  midx[n] = tlx * Wp + tly;
  mfxy[n] = make_float2(cx - (float)tlx, cy - (float)tly);
}

// ---------------- K2: fused gather(bf16 cols in LDS) + MFMA ----------------
// Block: 64 px x 64 out-ch, 256 thr = 4 waves (wave = 32o x 32px).
// K = 576 in 9 chunks of 64; cols LDS layout [buf][K/8][64px][8] bf16.
__global__ __launch_bounds__(256) void main_kernel(
    const float* __restrict__ xp, const unsigned short* __restrict__ Wb,
    const int* __restrict__ midx, const float2* __restrict__ mfxy,
    float* __restrict__ out) {
  int b  = blockIdx.x / 576;
  int l0 = (blockIdx.x % 576) * 64;

  __shared__ int    s_mi[9 * 64];
  __shared__ float2 s_mf[9 * 64];
  __shared__ unsigned short s_cols[2][8][64][8];

  int tid = threadIdx.x;

  // stage gather metadata for this pixel tile
  for (int e = tid; e < 576; e += 256) {
    int t = e >> 6, px = e & 63;
    s_mi[e] = midx[(b * 9 + t) * Lv + l0 + px];
    s_mf[e] = mfxy[(b * 9 + t) * Lv + l0 + px];
  }

  int px   = tid & 63;
  int lane = tid & 63;
  int iq   = __builtin_amdgcn_readfirstlane(tid >> 6);  // wave id 0..3
  int ow_  = (iq >> 1) * 32;     // wave o-offset
  int pw_  = (iq & 1) * 32;      // wave px-offset
  const float* xb = xp + b * NCIN * PLANE;

  f32x4 acc[2][2];
#pragma unroll
  for (int mt = 0; mt < 2; ++mt)
#pragma unroll
    for (int nt = 0; nt < 2; ++nt) acc[mt][nt] = (f32x4)0.f;

  __syncthreads();   // metadata ready

  // ---- gather one K-chunk (64 i) into s_cols[buf] ----
  auto gather = [&](int ch, int buf) {
#pragma unroll
    for (int s = 0; s < 2; ++s) {
      int gi = iq * 2 + s;                 // group 0..7
      int i0 = ch * 64 + gi * 8;
      short8 hv;
#pragma unroll
      for (int j = 0; j < 8; ++j) {
        int i = i0 + j;
        int c = (i * 7282) >> 16;          // i / 9 (exact for i < 3640)
        int t = i - c * 9;
        int   mi = s_mi[t * 64 + px];
        float2 f = s_mf[t * 64 + px];
        const float* p = xb + c * PLANE + mi;
        float ax = 1.f - f.x, ay = 1.f - f.y;
        float v = ax * ay * p[0] + ax * f.y * p[1] +
                  f.x * ay * p[Wp] + f.x * f.y * p[Wp + 1];
        hv[j] = (short)f2b(v);
      }
      *(short8*)&s_cols[buf][gi][px][0] = hv;
    }
  };

  gather(0, 0);
  __syncthreads();

  for (int ch = 0; ch < 9; ++ch) {
    int cur = ch & 1;
    if (ch < 8) gather(ch + 1, cur ^ 1);   // issue next-chunk loads first

    // ---- MFMA on buf[cur]: 2 K-steps x (2 o-tiles x 2 px-tiles) ----
#pragma unroll
    for (int ks = 0; ks < 2; ++ks) {
      int k = ch * 64 + ks * 32 + (lane >> 4) * 8;
      short8 a0 = *(const short8*)&Wb[(ow_ + (lane & 15)) * 576 + k];
      short8 a1 = *(const short8*)&Wb[(ow_ + 16 + (lane & 15)) * 576 + k];
      int kg = ks * 4 + (lane >> 4);
      short8 b0 = *(const short8*)&s_cols[cur][kg][pw_ + (lane & 15)][0];
      short8 b1 = *(const short8*)&s_cols[cur][kg][pw_ + 16 + (lane & 15)][0];
      acc[0][0] = __builtin_amdgcn_mfma_f32_16x16x32_bf16(a0, b0, acc[0][0], 0, 0, 0);
      acc[0][1] = __builtin_amdgcn_mfma_f32_16x16x32_bf16(a0, b1, acc[0][1], 0, 0, 0);
      acc[1][0] = __builtin_amdgcn_mfma_f32_16x16x32_bf16(a1, b0, acc[1][0], 0, 0, 0);
      acc[1][1] = __builtin_amdgcn_mfma_f32_16x16x32_bf16(a1, b1, acc[1][1], 0, 0, 0);
    }
    __syncthreads();
  }

  // ---- epilogue: D[o][px], row=(lane>>4)*4+j, col=lane&15 ----
  int rr = lane >> 4, cl = lane & 15;
#pragma unroll
  for (int mt = 0; mt < 2; ++mt)
#pragma unroll
    for (int nt = 0; nt < 2; ++nt)
#pragma unroll
      for (int j = 0; j < 4; ++j) {
        int o = ow_ + mt * 16 + rr * 4 + j;
        int l = l0 + pw_ + nt * 16 + cl;
        out[((size_t)(b * Cv + o)) * Lv + l] = acc[mt][nt][j];
      }
}

// ---------------- launch ----------------
extern "C" void kernel_launch(void* const* d_in, const int* in_sizes, int n_in,
                              void* d_out, int out_size, void* d_ws, size_t ws_size,
                              hipStream_t stream) {
  const float* x     = (const float*)d_in[0];
  const float* depth = (const float*)d_in[1];
  const float* wo    = (const float*)d_in[2];
  const float* bias  = (const float*)d_in[3];
  const float* wgt   = (const float*)d_in[4];
  float* out = (float*)d_out;

  float* xp   = (float*)d_ws;                       // XP_SZ
  float* offp = xp + XP_SZ;                         // 2 * OFF_SZ
  float* woT  = offp + 2 * OFF_SZ;                  // 10530 (pad to 10560)
  unsigned short* Wb = (unsigned short*)(woT + 10560);   // 36864 ushort
  int* midx   = (int*)(Wb + 36864);                 // NMETA
  float2* mfxy = (float2*)(midx + NMETA);           // NMETA float2

  pad_kernel<<<2048, 256, 0, stream>>>(x, depth, xp);
  prep_kernel<<<144, 256, 0, stream>>>(wgt, wo, Wb, woT);
  offconv_kernel<<<576, 256, 0, stream>>>(xp, woT, offp);
  meta_kernel<<<NMETA / 256, 256, 0, stream>>>(offp, bias, midx, mfxy);
  main_kernel<<<1152, 256, 0, stream>>>(xp, Wb, midx, mfxy, out);
}